// Round 1
// 717.047 us; speedup vs baseline: 1.0821x; 1.0821x over previous
//
#include <hip/hip_runtime.h>

#define BROWS 131072

typedef __attribute__((ext_vector_type(8))) __bf16 bf16x8;
typedef __attribute__((ext_vector_type(4))) __bf16 bf16x4;
typedef __attribute__((ext_vector_type(4))) float f32x4;

__device__ __forceinline__ float sigmoidf_(float x) {
    return 1.0f / (1.0f + __expf(-x));
}
__device__ __forceinline__ float tanhf_(float x) {
    return 1.0f - 2.0f / (__expf(2.0f * x) + 1.0f);
}

// ---------------------------------------------------------------------------
// Kernel 1: transpose W_gates rows 3..258 (h part) into bf16 WT[1024][256].
// Coalesced-write version: thread owns (c, k8..k8+7) -> one 16B bf16x8 store.
// Reads are stride-4KB scalars but Wg is 1 MB (L2-resident, read once).
// ---------------------------------------------------------------------------
__global__ __launch_bounds__(256)
void wt_kernel(const float* __restrict__ Wg, __bf16* __restrict__ WT) {
    int gid = blockIdx.x * 256 + threadIdx.x;    // 0..32767
    int c = gid >> 5;                            // 0..1023
    int k8 = (gid & 31) * 8;                     // 0..248
    bf16x8 v;
#pragma unroll
    for (int j = 0; j < 8; ++j)
        v[j] = (__bf16)Wg[(3 + k8 + j) * 1024 + c];
    *(bf16x8*)(WT + c * 256 + k8) = v;           // 16B coalesced store
}

// ---------------------------------------------------------------------------
// Kernel 2: switch counts. Thread-per-row via LDS-staged transpose.
// Block = 256 threads = 256 rows. h staged in 32-col chunks (coalesced float4
// loads) into pitch-33 LDS: read bank = (tid + c) % 32 -> 2 lanes/bank (free).
// Weights packed interleaved in LDS, read as broadcast float4.
// No cross-lane ops until the final ballot. sigmoid(s)>0.5 <=> s>0.
// ---------------------------------------------------------------------------
__global__ __launch_bounds__(256)
void switch_kernel(const float* __restrict__ x, const float* __restrict__ h,
                   const float* __restrict__ Wsw, const float* __restrict__ bsw,
                   int* __restrict__ cnt) {
    __shared__ float hs[256 * 33];               // 33 KB, pitch 33 (odd)
    __shared__ float wpk[512];                   // interleaved {w0,w1} pairs
    const int tid = threadIdx.x;
    const int r0 = blockIdx.x * 256;

    // stage h-part switch weights (rows 3..258), interleaved
    *(float2*)&wpk[2 * tid] = *(const float2*)&Wsw[(3 + tid) * 2];

    // x part + bias (uniform scalar weight loads)
    const int row = r0 + tid;
    const float x0 = x[row * 3 + 0];
    const float x1 = x[row * 3 + 1];
    const float x2 = x[row * 3 + 2];
    float si = x0 * Wsw[0] + x1 * Wsw[2] + x2 * Wsw[4] + bsw[0];
    float sg = x0 * Wsw[1] + x1 * Wsw[3] + x2 * Wsw[5] + bsw[1];

    for (int kc = 0; kc < 8; ++kc) {
        __syncthreads();                         // protect hs (and wpk on kc=0)
#pragma unroll
        for (int i = 0; i < 8; ++i) {
            int idx = tid + 256 * i;             // 0..2047
            int r = idx >> 3;                    // 0..255
            int c4 = (idx & 7) * 4;              // 0..28
            float4 v = *(const float4*)(h + (r0 + r) * 256 + kc * 32 + c4);
            hs[r * 33 + c4 + 0] = v.x;
            hs[r * 33 + c4 + 1] = v.y;
            hs[r * 33 + c4 + 2] = v.z;
            hs[r * 33 + c4 + 3] = v.w;
        }
        __syncthreads();
#pragma unroll
        for (int c2 = 0; c2 < 16; ++c2) {
            float4 wv = *(const float4*)&wpk[kc * 64 + c2 * 4]; // broadcast
            float v0 = hs[tid * 33 + c2 * 2 + 0];
            float v1 = hs[tid * 33 + c2 * 2 + 1];
            si += v0 * wv.x + v1 * wv.z;
            sg += v0 * wv.y + v1 * wv.w;
        }
    }

    unsigned long long bi = __ballot(si > 0.0f);
    unsigned long long bgm = __ballot(sg > 0.0f);
    if ((tid & 63) == 0) {
        atomicAdd(&cnt[0], (int)__popcll(bi));
        atomicAdd(&cnt[1], (int)__popcll(bgm));
    }
}

// ---------------------------------------------------------------------------
// Kernel 3: main GEMM + LSTM epilogue (unchanged core).
// Grid linearized to 8192 blocks with bijective XCD-chunked swizzle:
// XCD x gets m-tiles [x*128, (x+1)*128); the 8 j0 siblings of one m-tile are
// consecutive in per-XCD sequence -> the 128KB h tile is fetched once per XCD.
// ---------------------------------------------------------------------------
__global__ __launch_bounds__(256)
void lstm_main(const float* __restrict__ x,      // B x 3
               const float* __restrict__ h,      // B x 256
               const float* __restrict__ c_cur,  // B x 256
               const float* __restrict__ Wg,     // 259 x 1024 (fp32)
               const float* __restrict__ bg,     // 1024
               const __bf16* __restrict__ WT,    // 1024 x 256 bf16 (B^T)
               const int* __restrict__ cnt,
               float* __restrict__ out) {
    __shared__ __bf16 A_lds[128 * 40];           // pitch 40 bf16 = 80 B

    const int tid = threadIdx.x;
    const int lane = tid & 63;
    const int w = tid >> 6;
    const int q = lane >> 4;
    const int ln = lane & 15;

    // XCD-chunked swizzle: bid -> (m-tile, j0-block)
    const int bid = blockIdx.x;                  // 0..8191
    const int jseq = bid >> 3;                   // 0..1023 per-XCD sequence
    const int m0 = (((bid & 7) << 7) + (jseq >> 3)) << 7;  // m-tile * 128
    const int j0 = (jseq & 7) << 5;              // h-col block * 32

    const int wrow = (w >> 1) * 64;
    const int colh = j0 + (w & 1) * 16 + ln;     // h column 0..255

    const int ci = cnt[0], cg = cnt[1];          // thr = B*0.5 = 65536 exactly
    const bool cond_i = (cg < 65536) && (ci > 65536);
    const bool cond_g = (cg > 65536) && (ci < 65536);

    // ---- accumulator init: bias + input @ W_gates[0:3] ----
    f32x4 acc[4][4];
    float bcol[4], wx0[4], wx1[4], wx2[4];
#pragma unroll
    for (int nt = 0; nt < 4; ++nt) {
        int colg = nt * 256 + colh;
        bcol[nt] = bg[colg];
        wx0[nt] = Wg[0 * 1024 + colg];
        wx1[nt] = Wg[1 * 1024 + colg];
        wx2[nt] = Wg[2 * 1024 + colg];
    }
#pragma unroll
    for (int mt = 0; mt < 4; ++mt) {
#pragma unroll
        for (int r = 0; r < 4; ++r) {
            int row = m0 + wrow + mt * 16 + q * 4 + r;
            float x0 = x[row * 3 + 0];
            float x1 = x[row * 3 + 1];
            float x2 = x[row * 3 + 2];
#pragma unroll
            for (int nt = 0; nt < 4; ++nt) {
                acc[mt][nt][r] = bcol[nt] + x0 * wx0[nt] + x1 * wx1[nt] + x2 * wx2[nt];
            }
        }
    }

    // ---- K loop: 8 chunks of K=32 over h columns ----
    float4 areg[4];
#pragma unroll
    for (int i = 0; i < 4; ++i) {
        int idx = tid + 256 * i;
        int row = idx >> 3, kq = idx & 7;
        areg[i] = *(const float4*)(h + (m0 + row) * 256 + 0 * 32 + kq * 4);
    }

    const __bf16* wtb[4];
#pragma unroll
    for (int nt = 0; nt < 4; ++nt)
        wtb[nt] = WT + (nt * 256 + colh) * 256 + q * 8;

    for (int kc = 0; kc < 8; ++kc) {
        if (kc) __syncthreads();                 // protect LDS from prior readers
#pragma unroll
        for (int i = 0; i < 4; ++i) {
            int idx = tid + 256 * i;
            int row = idx >> 3, kq = idx & 7;
            bf16x4 v;
            v[0] = (__bf16)areg[i].x;
            v[1] = (__bf16)areg[i].y;
            v[2] = (__bf16)areg[i].z;
            v[3] = (__bf16)areg[i].w;
            *(bf16x4*)(&A_lds[row * 40 + kq * 4]) = v;
        }
        __syncthreads();
        if (kc < 7) {
#pragma unroll
            for (int i = 0; i < 4; ++i) {
                int idx = tid + 256 * i;
                int row = idx >> 3, kq = idx & 7;
                areg[i] = *(const float4*)(h + (m0 + row) * 256 + (kc + 1) * 32 + kq * 4);
            }
        }
        bf16x8 bfrag[4];
#pragma unroll
        for (int nt = 0; nt < 4; ++nt)
            bfrag[nt] = *(const bf16x8*)(wtb[nt] + kc * 32);
        bf16x8 afrag[4];
#pragma unroll
        for (int mt = 0; mt < 4; ++mt)
            afrag[mt] = *(const bf16x8*)(&A_lds[(wrow + mt * 16 + ln) * 40 + q * 8]);
#pragma unroll
        for (int mt = 0; mt < 4; ++mt)
#pragma unroll
            for (int nt = 0; nt < 4; ++nt)
                acc[mt][nt] = __builtin_amdgcn_mfma_f32_16x16x32_bf16(
                    afrag[mt], bfrag[nt], acc[mt][nt], 0, 0, 0);
    }

    // ---- epilogue: per lane, acc[mt][nt][r] = gate nt at (row, colh) ----
#pragma unroll
    for (int mt = 0; mt < 4; ++mt) {
#pragma unroll
        for (int r = 0; r < 4; ++r) {
            int row = m0 + wrow + mt * 16 + q * 4 + r;
            float gi = sigmoidf_(acc[mt][0][r]);
            float gf = sigmoidf_(acc[mt][1][r]);
            float gg = tanhf_(acc[mt][2][r]);
            float go = sigmoidf_(acc[mt][3][r]);
            float c = c_cur[row * 256 + colh];
            float X = cond_i ? gi : (cond_g ? gg : gi * gg);
            float cn = gf * c + X;
            float hn = go * tanhf_(cn);
            out[row * 256 + colh] = hn;
            out[BROWS * 256 + row * 256 + colh] = cn;
        }
    }
}

// ---------------------------------------------------------------------------
extern "C" void kernel_launch(void* const* d_in, const int* in_sizes, int n_in,
                              void* d_out, int out_size, void* d_ws, size_t ws_size,
                              hipStream_t stream) {
    const float* x   = (const float*)d_in[0];   // input_tensor B x 3
    const float* h   = (const float*)d_in[1];   // h_cur B x 256
    const float* c   = (const float*)d_in[2];   // c_cur B x 256
    const float* Wg  = (const float*)d_in[3];   // W_gates 259 x 1024
    const float* bg  = (const float*)d_in[4];   // b_gates 1024
    const float* Wsw = (const float*)d_in[5];   // W_switch 259 x 2
    const float* bsw = (const float*)d_in[6];   // b_switch 2
    float* out = (float*)d_out;

    int* cnt = (int*)d_ws;
    __bf16* WT = (__bf16*)((char*)d_ws + 1024);  // 1024*256*2 = 512 KB

    hipMemsetAsync(d_ws, 0, 8, stream);
    wt_kernel<<<128, 256, 0, stream>>>(Wg, WT);
    switch_kernel<<<512, 256, 0, stream>>>(x, h, Wsw, bsw, cnt);
    lstm_main<<<8192, 256, 0, stream>>>(x, h, c, Wg, bg, WT, cnt, out);
}